// Round 10
// baseline (3572.578 us; speedup 1.0000x reference)
//
#include <hip/hip_runtime.h>
#include <cstdint>

#define TT 512

typedef float f32x16 __attribute__((ext_vector_type(16)));
typedef short s16x8 __attribute__((ext_vector_type(8)));
typedef unsigned short u16x4 __attribute__((ext_vector_type(4)));

// ---------------- threefry2x32 (exact JAX semantics) ----------------
__host__ __device__ inline void tf2x32(uint32_t k0, uint32_t k1, uint32_t& x0, uint32_t& x1) {
  uint32_t k2 = k0 ^ k1 ^ 0x1BD11BDAu;
#define TF_R(r) { x0 += x1; x1 = (x1 << r) | (x1 >> (32 - r)); x1 ^= x0; }
  x0 += k0; x1 += k1;
  TF_R(13) TF_R(15) TF_R(26) TF_R(6)
  x0 += k1; x1 += k2 + 1u;
  TF_R(17) TF_R(29) TF_R(16) TF_R(24)
  x0 += k2; x1 += k0 + 2u;
  TF_R(13) TF_R(15) TF_R(26) TF_R(6)
  x0 += k0; x1 += k1 + 3u;
  TF_R(17) TF_R(29) TF_R(16) TF_R(24)
  x0 += k1; x1 += k2 + 4u;
  TF_R(13) TF_R(15) TF_R(26) TF_R(6)
  x0 += k2; x1 += k0 + 5u;
#undef TF_R
}

struct KParams {
  const float* input;
  const float* w_ih[4];
  const float* w_hh[4];
  const float* b_ih[4];
  const float* b_hh[4];
  const float* w_lin;
  const float* b_lin;
  unsigned short* hLLC;   // [8][2][32768] bf16 — LLC copy (sc0 sc1)
  unsigned short* hL2;    // [8][2][32768] bf16 — per-XCD L2 copy (sc0)
  uint32_t* fOWN;         // [8][4][32 lines x 128B] per-WG own-stores-done epochs
  uint32_t* fBELOW;       // [8][4][32 lines] per-WG below(hLLC)-stores-done epochs
  uint32_t* fRD;          // [8][4][32 lines] per-WG reads-done epochs
  uint32_t* ep;           // [3][8] x 128B relay epochs: 0=own 1=below 2=readsdone
  uint32_t* xcdtab;       // [256]
  uint32_t* initcnt;      // [1]
  float* out;             // [128][512]
  uint32_t mk[4][2];      // per-layer threefry subkeys (partitionable split)
};

__device__ __forceinline__ unsigned short f2bf(float v) {
  uint32_t u = __float_as_uint(v);
  u += 0x7FFFu + ((u >> 16) & 1u);      // RNE
  return (unsigned short)(u >> 16);
}
__device__ __forceinline__ float bf2f(unsigned short b) {
  return __uint_as_float(((uint32_t)b) << 16);
}
__device__ __forceinline__ float sigm(float x) { return 1.f / (1.f + __expf(-x)); }
__device__ __forceinline__ float tanh_fast(float x) {
  float a = fabsf(x);
  float e = __expf(-2.f * a);
  float r = (1.f - e) / (1.f + e);
  return copysignf(r, x);
}

#define MFMA(A, Bv, C) __builtin_amdgcn_mfma_f32_32x32x16_bf16((A), (Bv), (C), 0, 0, 0)

// counted vmcnt wait (a = load-pairs still allowed in flight)
__device__ __forceinline__ void vmwait_dyn(int a) {
  switch (a) {
    case 0: asm volatile("s_waitcnt vmcnt(0)" ::: "memory"); break;
    case 1: asm volatile("s_waitcnt vmcnt(2)" ::: "memory"); break;
    case 2: asm volatile("s_waitcnt vmcnt(4)" ::: "memory"); break;
    case 3: asm volatile("s_waitcnt vmcnt(6)" ::: "memory"); break;
    case 4: asm volatile("s_waitcnt vmcnt(8)" ::: "memory"); break;
    case 5: asm volatile("s_waitcnt vmcnt(10)" ::: "memory"); break;
    case 6: asm volatile("s_waitcnt vmcnt(12)" ::: "memory"); break;
    default: asm volatile("s_waitcnt vmcnt(14)" ::: "memory"); break;
  }
  __builtin_amdgcn_sched_barrier(0);
}

#define ISSUE_LLC(s0, s1, ptr) \
  asm volatile("global_load_dwordx4 %0, %2, off sc0 sc1\n\t" \
               "global_load_dwordx4 %1, %2, off offset:1024 sc0 sc1" \
               : "=&v"(s0), "=&v"(s1) : "v"(ptr) : "memory")
#define ISSUE_L2(s0, s1, ptr) \
  asm volatile("global_load_dwordx4 %0, %2, off sc0\n\t" \
               "global_load_dwordx4 %1, %2, off offset:1024 sc0" \
               : "=&v"(s0), "=&v"(s1) : "v"(ptr) : "memory")

// 8-iteration GEMM half: frags FRAGBASE..FRAGBASE+7, software-pipelined.
// PRECONDITION: vmcnt == 0 on entry.
template <int FRAGBASE, bool L2MODE>
__device__ __forceinline__ void gemm8(const unsigned short* buf,
                                      const s16x8 (&Whi)[2][16], const s16x8 (&Wlo)[2][16],
                                      int wave, int lane,
                                      f32x16& a00, f32x16& a01, f32x16& a10, f32x16& a11) {
  s16x8 st[8][2];
  const int lofs = wave * 1024 + lane * 8;   // blk = i*4 + wave
#pragma unroll
  for (int i = 0; i < 8; ++i) {
    const unsigned short* ptr = buf + i * 4096 + lofs;
    if constexpr (L2MODE) { ISSUE_L2(st[i][0], st[i][1], ptr); }
    else                  { ISSUE_LLC(st[i][0], st[i][1], ptr); }
  }
#pragma unroll
  for (int i = 0; i < 8; ++i) {
    vmwait_dyn(7 - i);
    s16x8 bh0 = st[i][0];
    s16x8 bh1 = st[i][1];
    a00 = MFMA(Whi[0][FRAGBASE + i], bh0, a00);
    a10 = MFMA(Whi[1][FRAGBASE + i], bh0, a10);
    a01 = MFMA(Whi[0][FRAGBASE + i], bh1, a01);
    a11 = MFMA(Whi[1][FRAGBASE + i], bh1, a11);
    a00 = MFMA(Wlo[0][FRAGBASE + i], bh0, a00);
    a10 = MFMA(Wlo[1][FRAGBASE + i], bh0, a10);
    a01 = MFMA(Wlo[0][FRAGBASE + i], bh1, a01);
    a11 = MFMA(Wlo[1][FRAGBASE + i], bh1, a11);
  }
}

// hot poll of a single relay-epoch dword (all lanes same address -> broadcast)
__device__ __forceinline__ void pollep(const uint32_t* ep, uint32_t want) {
  while (__hip_atomic_load(ep, __ATOMIC_RELAXED, __HIP_MEMORY_SCOPE_AGENT) < want) {}
}
// aggregate 32 per-WG flag lines (lane i polls line i) then publish relay epoch
__device__ __forceinline__ void agg_publish(const uint32_t* fbase, uint32_t want,
                                            uint32_t* ep, uint32_t pub, int lane) {
  const uint32_t* my = fbase + (size_t)(lane & 31) * 32;
  while (true) {
    uint32_t v = __hip_atomic_load(my, __ATOMIC_RELAXED, __HIP_MEMORY_SCOPE_AGENT);
    if (__all(v >= want)) break;
  }
  if (lane == 0)
    __hip_atomic_store(ep, pub, __ATOMIC_RELAXED, __HIP_MEMORY_SCOPE_AGENT);
  asm volatile("s_waitcnt vmcnt(0)" ::: "memory");
}

__global__ __launch_bounds__(256, 1) void lstm4(KParams P) {
  const int wg   = blockIdx.x;
  const int grp  = wg & 7;       // (layer, half) — one XCD per group under round-robin
  const int iwg  = wg >> 3;      // 0..31: which 16-unit slice
  const int l    = grp >> 1;
  const int p    = grp & 1;
  const int tid  = threadIdx.x;
  const int wave = tid >> 6;
  const int lane = tid & 63;

  __shared__ float part[4][64][64];   // 64 KB
  __shared__ float bias_s[64];
  __shared__ float wih1_s[64];
  __shared__ float wlin_s[16];
  __shared__ float red_s[4][64];
  __shared__ uint32_t xs[8];
  __shared__ uint32_t barflag;

  // flag-line addressing: line (g, slot, iwg) = base + ((g*4+slot)*32 + iwg)*32 dwords
#define FL(base, g, slot) ((base) + (((size_t)(g) * 4 + (slot)) * 32) * 32)
#define EPP(kind, g) (P.ep + ((kind) * 8 + (g)) * 32)

  // ---- XCD identity probe
  uint32_t xcd;
  asm volatile("s_getreg_b32 %0, hwreg(20, 0, 4)" : "=s"(xcd));
  if (tid == 0) {
    __hip_atomic_store(&P.xcdtab[wg], xcd, __ATOMIC_RELAXED, __HIP_MEMORY_SCOPE_AGENT);
    asm volatile("s_waitcnt vmcnt(0)" ::: "memory");
    __hip_atomic_fetch_add(P.initcnt, 1u, __ATOMIC_RELAXED, __HIP_MEMORY_SCOPE_AGENT);
  }

  // ---- weight fragments (hi + lo bf16) into registers
  s16x8 Whi[2][16], Wlo[2][16];
  {
#pragma unroll
    for (int ji = 0; ji < 16; ++ji) {
      const bool valid = (l > 0) || (ji < 8);
      const float* wsrc = (l == 0 || ji >= 8) ? P.w_hh[l] : P.w_ih[l];
      const int blk = (ji & 7) * 4 + wave;
      const int col = blk * 16 + (lane >> 5) * 8;
#pragma unroll
      for (int m = 0; m < 2; ++m) {
        const int rl = m * 32 + (lane & 31);
        const int grow = (rl >> 4) * 512 + iwg * 16 + (rl & 15);
        s16x8 h8 = {0, 0, 0, 0, 0, 0, 0, 0};
        s16x8 l8 = {0, 0, 0, 0, 0, 0, 0, 0};
        if (valid) {
          const float* s = wsrc + grow * 512 + col;
#pragma unroll
          for (int e = 0; e < 8; ++e) {
            float v = s[e];
            unsigned short hb = f2bf(v);
            h8[e] = (short)hb;
            l8[e] = (short)f2bf(v - bf2f(hb));
          }
        }
        Whi[m][ji] = h8;
        Wlo[m][ji] = l8;
      }
    }
  }
  if (tid < 64) {
    const int rl = tid;
    const int grow = (rl >> 4) * 512 + iwg * 16 + (rl & 15);
    bias_s[rl] = P.b_ih[l][grow] + P.b_hh[l][grow];
    wih1_s[rl] = (l == 0) ? P.w_ih[0][grow] : 0.f;
  }
  if (l == 3 && tid < 16) wlin_s[tid] = P.w_lin[iwg * 16 + tid];

  // ---- bounded grid init barrier (timeout -> LLC-only fallback, never hang)
  if (tid == 0) {
    uint32_t okv = 1u, tries = 0u;
    while (__hip_atomic_load(P.initcnt, __ATOMIC_RELAXED, __HIP_MEMORY_SCOPE_AGENT) < 256u) {
      __builtin_amdgcn_s_sleep(8);
      if (++tries > (1u << 17)) { okv = 0u; break; }
    }
    barflag = okv;
  }
  __syncthreads();
  const bool bar_ok = (barflag != 0u);

  // ---- XCD-mapping verification
  uint32_t va = __hip_atomic_load(&P.xcdtab[tid], __ATOMIC_RELAXED, __HIP_MEMORY_SCOPE_AGENT);
  uint32_t vb = __hip_atomic_load(&P.xcdtab[tid & 7], __ATOMIC_RELAXED, __HIP_MEMORY_SCOPE_AGENT);
  int ok1 = __syncthreads_and((va == vb) ? 1 : 0);
  if (tid < 8) xs[tid] = vb;
  __syncthreads();
  bool dis = true;
#pragma unroll
  for (int a = 0; a < 8; ++a)
#pragma unroll
    for (int b = a + 1; b < 8; ++b)
      if (xs[a] == xs[b]) dis = false;
  const bool l2ok = bar_ok && (ok1 != 0) && dis;
  __syncthreads();

  const int gb = p * 64 + lane;
  const uint32_t kk0 = P.mk[l][0], kk1 = P.mk[l][1];
  float cst[4] = {0.f, 0.f, 0.f, 0.f};

  for (int t = 0; t < TT; ++t) {
    float xin = 0.f;
    if (l == 0) xin = P.input[gb * 512 + t];

    // ---------- consumer-side relay aggregations (one designated wave each) ----------
    if (iwg == 0 && wave == 1 && t > 0)          // own-epoch (critical edge)
      agg_publish(FL(P.fOWN, grp, (t - 1) & 3), (uint32_t)t, EPP(0, grp), (uint32_t)t, lane);
    if (iwg == 1 && wave == 0 && l > 0)          // below-epoch
      agg_publish(FL(P.fBELOW, grp - 2, t & 3), (uint32_t)(t + 1), EPP(1, grp), (uint32_t)(t + 1), lane);
    if (iwg == 2 && wave == 2 && l < 3 && t >= 2)  // reads-done epoch (eviction guard)
      agg_publish(FL(P.fRD, grp + 2, (t - 2) & 3), (uint32_t)(t - 1), EPP(2, grp), (uint32_t)(t - 1), lane);

    f32x16 a00 = {0,0,0,0,0,0,0,0,0,0,0,0,0,0,0,0};
    f32x16 a01 = {0,0,0,0,0,0,0,0,0,0,0,0,0,0,0,0};
    f32x16 a10 = {0,0,0,0,0,0,0,0,0,0,0,0,0,0,0,0};
    f32x16 a11 = {0,0,0,0,0,0,0,0,0,0,0,0,0,0,0,0};

    const unsigned short* pB    = P.hLLC + (size_t)(((l - 1) * 2 + p) * 2 + (t & 1)) * 32768;
    const unsigned short* pOL2  = P.hL2  + (size_t)(grp * 2 + ((t - 1) & 1)) * 32768;
    const unsigned short* pOLLC = P.hLLC + (size_t)(grp * 2 + ((t - 1) & 1)) * 32768;

    // ---- phase A: below-half GEMM
    if (l > 0) {
      if (!(iwg == 1 && wave == 0)) pollep(EPP(1, grp), (uint32_t)(t + 1));
      asm volatile("s_waitcnt vmcnt(0)" ::: "memory");
      gemm8<0, false>(pB, Whi, Wlo, wave, lane, a00, a01, a10, a11);
    }
    // ---- phase B: own-half GEMM (critical recurrent edge)
    if (t > 0) {
      if (!(iwg == 0 && wave == 1)) pollep(EPP(0, grp), (uint32_t)t);
      asm volatile("s_waitcnt vmcnt(0)" ::: "memory");
      if (l > 0) {
        if (l2ok) gemm8<8, true >(pOL2,  Whi, Wlo, wave, lane, a00, a01, a10, a11);
        else      gemm8<8, false>(pOLLC, Whi, Wlo, wave, lane, a00, a01, a10, a11);
      } else {
        if (l2ok) gemm8<0, true >(pOL2,  Whi, Wlo, wave, lane, a00, a01, a10, a11);
        else      gemm8<0, false>(pOLLC, Whi, Wlo, wave, lane, a00, a01, a10, a11);
      }
    }

    // ---- single-phase cross-wave k-split reduction ----
#pragma unroll
    for (int r = 0; r < 16; ++r) {
      const int row = (r & 3) + 8 * (r >> 2) + 4 * (lane >> 5);
      const int cl = lane & 31;
      part[wave][row][cl]           = a00[r];
      part[wave][row][32 + cl]      = a01[r];
      part[wave][32 + row][cl]      = a10[r];
      part[wave][32 + row][32 + cl] = a11[r];
    }

    // dropout factors (threefry) in the barrier shadow
    float fac[4];
#pragma unroll
    for (int cc = 0; cc < 4; ++cc) {
      const int gu = iwg * 16 + wave * 4 + cc;
      uint32_t j = ((uint32_t)t * 128u + (uint32_t)gb) * 512u + (uint32_t)gu;
      uint32_t x0 = 0u, x1 = j;
      tf2x32(kk0, kk1, x0, x1);
      fac[cc] = ((x0 ^ x1) & 0x80000000u) ? 0.f : 2.f;
    }
    __syncthreads();
    // reads-done publish: all waves' GEMM loads retired before the barrier
    if (tid == 0 && l > 0)
      __hip_atomic_store(FL(P.fRD, grp, t & 3) + (size_t)iwg * 32, (uint32_t)(t + 1),
                         __ATOMIC_RELAXED, __HIP_MEMORY_SCOPE_AGENT);

    float si[4], sf[4], sg[4], so[4];
#pragma unroll
    for (int cc = 0; cc < 4; ++cc) {
      const int ul = wave * 4 + cc;
      si[cc] = part[0][ul][lane]      + part[1][ul][lane]      + part[2][ul][lane]      + part[3][ul][lane];
      sf[cc] = part[0][16 + ul][lane] + part[1][16 + ul][lane] + part[2][16 + ul][lane] + part[3][16 + ul][lane];
      sg[cc] = part[0][32 + ul][lane] + part[1][32 + ul][lane] + part[2][32 + ul][lane] + part[3][32 + ul][lane];
      so[cc] = part[0][48 + ul][lane] + part[1][48 + ul][lane] + part[2][48 + ul][lane] + part[3][48 + ul][lane];
    }

    // ---- elementwise LSTM cell ----
    float osum = 0.f;
    u16x4 hv;
#pragma unroll
    for (int cc = 0; cc < 4; ++cc) {
      const int ul = wave * 4 + cc;
      float pi = si[cc] + bias_s[ul];
      float pf = sf[cc] + bias_s[16 + ul];
      float pg = sg[cc] + bias_s[32 + ul];
      float po = so[cc] + bias_s[48 + ul];
      if (l == 0) {
        pi += wih1_s[ul] * xin;
        pf += wih1_s[16 + ul] * xin;
        pg += wih1_s[32 + ul] * xin;
        po += wih1_s[48 + ul] * xin;
      }
      float ig = sigm(pi), fg = sigm(pf), gg = tanh_fast(pg), og = sigm(po);
      float cn = fg * cst[cc] + ig * gg;
      cst[cc] = cn;
      float hh = og * tanh_fast(cn) * fac[cc];
      hv[cc] = f2bf(hh);
      if (l == 3) osum += hh * wlin_s[ul];
    }

    // ---- eviction guard: layer-above finished reading our hLLC slot (t-2)
    if (l < 3 && t >= 2)
      pollep(EPP(2, grp), (uint32_t)(t - 1));

    // ---- stores: hL2 first (fast ack), then hLLC; early own-publish on L2 ack ----
    {
      const int elem = ((iwg * 2 + (lane >> 5)) * 64 + (wave >> 1) * 32 + (lane & 31)) * 8 + (wave & 1) * 4;
      unsigned short* wLLC = P.hLLC + (size_t)(grp * 2 + (t & 1)) * 32768 + elem;
      unsigned short* wL2  = P.hL2  + (size_t)(grp * 2 + (t & 1)) * 32768 + elem;
      const bool llcstore = (l < 3) || (!l2ok);
      if (l2ok)
        asm volatile("global_store_dwordx2 %0, %1, off sc0" :: "v"(wL2), "v"(hv) : "memory");
      if (llcstore)
        asm volatile("global_store_dwordx2 %0, %1, off sc0 sc1" :: "v"(wLLC), "v"(hv) : "memory");

      if (l2ok) {
        if (llcstore) { asm volatile("s_waitcnt vmcnt(1)" ::: "memory"); }
        else          { asm volatile("s_waitcnt vmcnt(0)" ::: "memory"); }
        __syncthreads();
        if (tid == 0)   // own-ready: hL2 copy acked (own consumers read hL2)
          __hip_atomic_store(FL(P.fOWN, grp, t & 3) + (size_t)iwg * 32, (uint32_t)(t + 1),
                             __ATOMIC_RELAXED, __HIP_MEMORY_SCOPE_AGENT);
        if (llcstore) {
          asm volatile("s_waitcnt vmcnt(0)" ::: "memory");
          __syncthreads();
          if (tid == 0 && l < 3)
            __hip_atomic_store(FL(P.fBELOW, grp, t & 3) + (size_t)iwg * 32, (uint32_t)(t + 1),
                               __ATOMIC_RELAXED, __HIP_MEMORY_SCOPE_AGENT);
        }
      } else {
        asm volatile("s_waitcnt vmcnt(0)" ::: "memory");
        __syncthreads();
        if (tid == 0) {
          __hip_atomic_store(FL(P.fOWN, grp, t & 3) + (size_t)iwg * 32, (uint32_t)(t + 1),
                             __ATOMIC_RELAXED, __HIP_MEMORY_SCOPE_AGENT);
          if (l < 3)
            __hip_atomic_store(FL(P.fBELOW, grp, t & 3) + (size_t)iwg * 32, (uint32_t)(t + 1),
                               __ATOMIC_RELAXED, __HIP_MEMORY_SCOPE_AGENT);
        }
      }
    }

    // ---- layer-3 projection (after publish) ----
    if (l == 3) {
      red_s[wave][lane] = osum;
      __syncthreads();
      if (tid < 64) {
        float v = red_s[0][tid] + red_s[1][tid] + red_s[2][tid] + red_s[3][tid];
        if (iwg == 0) v += P.b_lin[0];
        atomicAdd(&P.out[(p * 64 + tid) * 512 + t], v);
      }
    }
  }
#undef FL
#undef EPP
}

extern "C" void kernel_launch(void* const* d_in, const int* in_sizes, int n_in,
                              void* d_out, int out_size, void* d_ws, size_t ws_size,
                              hipStream_t stream) {
  (void)in_sizes; (void)n_in; (void)ws_size;
  KParams P;
  P.input = (const float*)d_in[0];
  for (int l = 0; l < 4; ++l) {
    P.w_ih[l] = (const float*)d_in[1 + 4 * l];
    P.w_hh[l] = (const float*)d_in[2 + 4 * l];
    P.b_ih[l] = (const float*)d_in[3 + 4 * l];
    P.b_hh[l] = (const float*)d_in[4 + 4 * l];
  }
  P.w_lin = (const float*)d_in[17];
  P.b_lin = (const float*)d_in[18];
  unsigned char* ws = (unsigned char*)d_ws;
  P.hLLC    = (unsigned short*)(ws);                          // 1 MB   [8][2][32768]
  P.hL2     = (unsigned short*)(ws + (1u << 20));             // 1 MB   [8][2][32768]
  P.fOWN    = (uint32_t*)(ws + (2u << 20));                   // 128 KB [8][4][32]x128B
  P.fBELOW  = (uint32_t*)(ws + (2u << 20) + (128u << 10));    // 128 KB
  P.fRD     = (uint32_t*)(ws + (2u << 20) + (256u << 10));    // 128 KB
  P.ep      = (uint32_t*)(ws + (2u << 20) + (384u << 10));    // 3 KB   [3][8]x128B
  P.xcdtab  = (uint32_t*)(ws + (2u << 20) + (388u << 10));    // 1 KB
  P.initcnt = (uint32_t*)(ws + (2u << 20) + (389u << 10));
  P.out     = (float*)d_out;
  // total ws span ~2.38 MB (<= 2.62 MB proven by R2/R3)

  // subkeys = jax.random.split(key(42), 4) under threefry_partitionable=True
  for (uint32_t i = 0; i < 4; ++i) {
    uint32_t x0 = 0u, x1 = i;
    tf2x32(0u, 42u, x0, x1);
    P.mk[i][0] = x0; P.mk[i][1] = x1;
  }

  hipMemsetAsync(ws + (2u << 20), 0, (390u << 10), stream);   // all flags + epochs + xcdtab + initcnt
  hipMemsetAsync(d_out, 0, (size_t)out_size * sizeof(float), stream);
  hipLaunchKernelGGL(lstm4, dim3(256), dim3(256), 0, stream, P);
}

// Round 11
// 3459.900 us; speedup vs baseline: 1.0326x; 1.0326x over previous
//
#include <hip/hip_runtime.h>
#include <cstdint>

#define TT 512

typedef float f32x16 __attribute__((ext_vector_type(16)));
typedef short s16x8 __attribute__((ext_vector_type(8)));
typedef _Float16 f16x8 __attribute__((ext_vector_type(8)));

// ---------------- threefry2x32 (exact JAX semantics) ----------------
__host__ __device__ inline void tf2x32(uint32_t k0, uint32_t k1, uint32_t& x0, uint32_t& x1) {
  uint32_t k2 = k0 ^ k1 ^ 0x1BD11BDAu;
#define TF_R(r) { x0 += x1; x1 = (x1 << r) | (x1 >> (32 - r)); x1 ^= x0; }
  x0 += k0; x1 += k1;
  TF_R(13) TF_R(15) TF_R(26) TF_R(6)
  x0 += k1; x1 += k2 + 1u;
  TF_R(17) TF_R(29) TF_R(16) TF_R(24)
  x0 += k2; x1 += k0 + 2u;
  TF_R(13) TF_R(15) TF_R(26) TF_R(6)
  x0 += k0; x1 += k1 + 3u;
  TF_R(17) TF_R(29) TF_R(16) TF_R(24)
  x0 += k1; x1 += k2 + 4u;
  TF_R(13) TF_R(15) TF_R(26) TF_R(6)
  x0 += k2; x1 += k0 + 5u;
#undef TF_R
}

struct KParams {
  const float* input;
  const float* w_ih[4];
  const float* w_hh[4];
  const float* b_ih[4];
  const float* b_hh[4];
  const float* w_lin;
  const float* b_lin;
  unsigned short* hLLC;   // [16][2][16384] fp16 — LLC copy (sc0 sc1)
  unsigned short* hL2;    // [16][2][16384] fp16 — per-XCD L2 copy (sc0)
  uint32_t* cnt;          // kinds: 0=own-ready(L2 ack) 1=full-ready(LLC ack) 2=reads-done
  uint32_t* xcdtab;       // [512]
  uint32_t* initcnt;      // [1]
  float* out;             // [128][512]
  uint32_t mk[4][2];      // per-layer threefry subkeys (partitionable split)
};

__device__ __forceinline__ unsigned short f2h(float v) {
  _Float16 h = (_Float16)v;           // v_cvt_f16_f32, RNE
  return __builtin_bit_cast(unsigned short, h);
}
__device__ __forceinline__ float sigm(float x) { return 1.f / (1.f + __expf(-x)); }
__device__ __forceinline__ float tanh_fast(float x) {
  float a = fabsf(x);
  float e = __expf(-2.f * a);
  float r = (1.f - e) / (1.f + e);
  return copysignf(r, x);
}

#define MFMA16(A, B, C) __builtin_amdgcn_mfma_f32_32x32x16_f16((A), (B), (C), 0, 0, 0)

// counted vmcnt wait, 1 load per pipeline stage
__device__ __forceinline__ void vmwait1(int a) {
  switch (a) {
    case 0: asm volatile("s_waitcnt vmcnt(0)" ::: "memory"); break;
    case 1: asm volatile("s_waitcnt vmcnt(1)" ::: "memory"); break;
    case 2: asm volatile("s_waitcnt vmcnt(2)" ::: "memory"); break;
    case 3: asm volatile("s_waitcnt vmcnt(3)" ::: "memory"); break;
    case 4: asm volatile("s_waitcnt vmcnt(4)" ::: "memory"); break;
    case 5: asm volatile("s_waitcnt vmcnt(5)" ::: "memory"); break;
    case 6: asm volatile("s_waitcnt vmcnt(6)" ::: "memory"); break;
    default: asm volatile("s_waitcnt vmcnt(7)" ::: "memory"); break;
  }
  __builtin_amdgcn_sched_barrier(0);
}

#define ISSUE_LLC1(s0, ptr) \
  asm volatile("global_load_dwordx4 %0, %1, off sc0 sc1" : "=&v"(s0) : "v"(ptr) : "memory")
#define ISSUE_L21(s0, ptr) \
  asm volatile("global_load_dwordx4 %0, %1, off sc0" : "=&v"(s0) : "v"(ptr) : "memory")

// 8-iter GEMM half: frag FRAGBASE+i over k-block i*4+wave. PRECONDITION: vmcnt==0.
template <int FRAGBASE, bool L2MODE>
__device__ __forceinline__ void gemm8(const unsigned short* buf,
                                      const f16x8 (&W)[2][16],
                                      int wave, int lane, f32x16& a0, f32x16& a1) {
  s16x8 st[8];
  const int lofs = lane * 8;
#pragma unroll
  for (int i = 0; i < 8; ++i) {
    const unsigned short* p = buf + (i * 4 + wave) * 512 + lofs;
    if constexpr (L2MODE) { ISSUE_L21(st[i], p); } else { ISSUE_LLC1(st[i], p); }
  }
#pragma unroll
  for (int i = 0; i < 8; ++i) {
    vmwait1(7 - i);
    f16x8 b = __builtin_bit_cast(f16x8, st[i]);
    a0 = MFMA16(W[0][FRAGBASE + i], b, a0);
    a1 = MFMA16(W[1][FRAGBASE + i], b, a1);
  }
}

// single-dword monotone-counter poll (all lanes same address -> broadcast)
__device__ __forceinline__ void pollcnt(const uint32_t* p, uint32_t tgt, bool slp) {
  while (__hip_atomic_load(p, __ATOMIC_RELAXED, __HIP_MEMORY_SCOPE_AGENT) < tgt) {
    if (slp) __builtin_amdgcn_s_sleep(1);
  }
}
__device__ __forceinline__ uint32_t tgt_of(int T) { return 32u * ((uint32_t)(T >> 3) + 1u); }

__global__ __launch_bounds__(256, 2) void lstm4(KParams P) {
  const int wg   = blockIdx.x;
  const int g    = wg & 15;      // (layer, quarter); whole group on XCD g%8 under round-robin
  const int iwg  = wg >> 4;      // 0..31: which 16-unit slice (= its k-block)
  const int l    = g >> 2;
  const int q    = g & 3;
  const int tid  = threadIdx.x;
  const int wave = tid >> 6;
  const int lane = tid & 63;
  const int n    = lane & 31;    // batch within quarter
  const int hi   = lane >> 5;

  __shared__ float part[4][64][32];   // 32 KB: per-wave k-split partials
  __shared__ float bias_s[64];
  __shared__ float wih1_s[64];
  __shared__ float wlin_s[16];
  __shared__ float red_s[4][64];
  __shared__ uint32_t barflag;

#define CNT(kind, gg, slot) (P.cnt + (((kind) * 16 + (gg)) * 8 + (slot)) * 32)

  // ---- XCD identity probe
  uint32_t xcd;
  asm volatile("s_getreg_b32 %0, hwreg(20, 0, 4)" : "=s"(xcd));
  if (tid == 0) {
    __hip_atomic_store(&P.xcdtab[wg], xcd, __ATOMIC_RELAXED, __HIP_MEMORY_SCOPE_AGENT);
    asm volatile("s_waitcnt vmcnt(0)" ::: "memory");
    __hip_atomic_fetch_add(P.initcnt, 1u, __ATOMIC_RELAXED, __HIP_MEMORY_SCOPE_AGENT);
  }

  // ---- fp16 weight fragments into registers (single term)
  // frags 0..7 = below half (w_ih, l>0); frags 8..15 = own half (w_hh); l==0: frags 0..7 = w_hh
  f16x8 W[2][16];
  {
#pragma unroll
    for (int ji = 0; ji < 16; ++ji) {
      bool valid = true;
      const float* wsrc;
      if (l == 0) { valid = (ji < 8); wsrc = P.w_hh[0]; }
      else        { wsrc = (ji < 8) ? P.w_ih[l] : P.w_hh[l]; }
      const int blk = (ji & 7) * 4 + wave;
      const int col = blk * 16 + hi * 8;
#pragma unroll
      for (int m = 0; m < 2; ++m) {
        const int rl = m * 32 + n;
        const int grow = (rl >> 4) * 512 + iwg * 16 + (rl & 15);
        f16x8 v8 = {0, 0, 0, 0, 0, 0, 0, 0};
        if (valid) {
          const float* s = wsrc + grow * 512 + col;
#pragma unroll
          for (int e = 0; e < 8; ++e) v8[e] = (_Float16)s[e];
        }
        W[m][ji] = v8;
      }
    }
  }
  if (tid < 64) {
    const int rl = tid;
    const int grow = (rl >> 4) * 512 + iwg * 16 + (rl & 15);
    bias_s[rl] = P.b_ih[l][grow] + P.b_hh[l][grow];
    wih1_s[rl] = (l == 0) ? P.w_ih[0][grow] : 0.f;
  }
  if (l == 3 && tid < 16) wlin_s[tid] = P.w_lin[iwg * 16 + tid];

  // ---- bounded grid init barrier (512 WGs; timeout -> LLC fallback, never hang)
  if (tid == 0) {
    uint32_t okv = 1u, tries = 0u;
    while (__hip_atomic_load(P.initcnt, __ATOMIC_RELAXED, __HIP_MEMORY_SCOPE_AGENT) < 512u) {
      __builtin_amdgcn_s_sleep(8);
      if (++tries > (1u << 17)) { okv = 0u; break; }
    }
    barflag = okv;
  }
  __syncthreads();
  const bool bar_ok = (barflag != 0u);

  // ---- per-group XCD co-location check (the only L2-path requirement)
  uint32_t va = __hip_atomic_load(&P.xcdtab[tid], __ATOMIC_RELAXED, __HIP_MEMORY_SCOPE_AGENT);
  uint32_t vb = __hip_atomic_load(&P.xcdtab[tid & 15], __ATOMIC_RELAXED, __HIP_MEMORY_SCOPE_AGENT);
  uint32_t vc = __hip_atomic_load(&P.xcdtab[256 + tid], __ATOMIC_RELAXED, __HIP_MEMORY_SCOPE_AGENT);
  uint32_t vd = __hip_atomic_load(&P.xcdtab[(256 + tid) & 15], __ATOMIC_RELAXED, __HIP_MEMORY_SCOPE_AGENT);
  int ok1 = __syncthreads_and((va == vb && vc == vd) ? 1 : 0);
  const bool l2ok = bar_ok && (ok1 != 0);
  __syncthreads();

  const int gb = q * 32 + n;
  const uint32_t kk0 = P.mk[l][0], kk1 = P.mk[l][1];
  const int k0 = hi * 8 + wave * 2;   // this thread's 2 units: k0, k0+1 (within the 16)
  float cst[2] = {0.f, 0.f};

  for (int t = 0; t < TT; ++t) {
    float xin = 0.f;
    if (l == 0) xin = P.input[gb * 512 + t];

    f32x16 a0 = {0,0,0,0,0,0,0,0,0,0,0,0,0,0,0,0};
    f32x16 a1 = {0,0,0,0,0,0,0,0,0,0,0,0,0,0,0,0};

    const unsigned short* pB    = P.hLLC + (size_t)((g - 4) * 2 + (t & 1)) * 16384;
    const unsigned short* pOL2  = P.hL2  + (size_t)(g * 2 + ((t - 1) & 1)) * 16384;
    const unsigned short* pOLLC = P.hLLC + (size_t)(g * 2 + ((t - 1) & 1)) * 16384;

    // ---- phase A: below half (cross-layer edge, pipeline slack; hides own publish)
    if (l > 0) {
      pollcnt(CNT(1, g - 4, t & 7), tgt_of(t), true);
      asm volatile("s_waitcnt vmcnt(0)" ::: "memory");
      gemm8<0, false>(pB, W, wave, lane, a0, a1);
    }
    // ---- phase B: own half (critical recurrent edge)
    if (t > 0) {
      if (l2ok) pollcnt(CNT(0, g, (t - 1) & 7), tgt_of(t - 1), false);
      else      pollcnt(CNT(1, g, (t - 1) & 7), tgt_of(t - 1), false);
      asm volatile("s_waitcnt vmcnt(0)" ::: "memory");
      if (l > 0) {
        if (l2ok) gemm8<8, true >(pOL2,  W, wave, lane, a0, a1);
        else      gemm8<8, false>(pOLLC, W, wave, lane, a0, a1);
      } else {
        if (l2ok) gemm8<0, true >(pOL2,  W, wave, lane, a0, a1);
        else      gemm8<0, false>(pOLLC, W, wave, lane, a0, a1);
      }
    }

    // ---- cross-wave k-split reduction (single phase) ----
#pragma unroll
    for (int r = 0; r < 16; ++r) {
      const int row = (r & 3) + 8 * (r >> 2) + 4 * hi;
      part[wave][row][n]      = a0[r];
      part[wave][32 + row][n] = a1[r];
    }

    // dropout factors (threefry) in the barrier shadow — 2 units/thread
    float fac[2];
#pragma unroll
    for (int cc = 0; cc < 2; ++cc) {
      const int gu = iwg * 16 + k0 + cc;
      uint32_t j = ((uint32_t)t * 128u + (uint32_t)gb) * 512u + (uint32_t)gu;
      uint32_t x0 = 0u, x1 = j;
      tf2x32(kk0, kk1, x0, x1);
      fac[cc] = ((x0 ^ x1) & 0x80000000u) ? 0.f : 2.f;
    }
    __syncthreads();
    // reads-done publish (all waves' GEMM loads retired pre-barrier)
    if (tid == 0 && l > 0)
      __hip_atomic_fetch_add(CNT(2, g, t & 7), 1u, __ATOMIC_RELAXED, __HIP_MEMORY_SCOPE_AGENT);

    // ---- elementwise LSTM cell (2 units) ----
    float hh[2];
#pragma unroll
    for (int cc = 0; cc < 2; ++cc) {
      const int k = k0 + cc;
      float si = part[0][k][n]      + part[1][k][n]      + part[2][k][n]      + part[3][k][n];
      float sf = part[0][16 + k][n] + part[1][16 + k][n] + part[2][16 + k][n] + part[3][16 + k][n];
      float sg = part[0][32 + k][n] + part[1][32 + k][n] + part[2][32 + k][n] + part[3][32 + k][n];
      float so = part[0][48 + k][n] + part[1][48 + k][n] + part[2][48 + k][n] + part[3][48 + k][n];
      float pi = si + bias_s[k];
      float pf = sf + bias_s[16 + k];
      float pg = sg + bias_s[32 + k];
      float po = so + bias_s[48 + k];
      if (l == 0) {
        pi += wih1_s[k] * xin;
        pf += wih1_s[16 + k] * xin;
        pg += wih1_s[32 + k] * xin;
        po += wih1_s[48 + k] * xin;
      }
      float ig = sigm(pi), fg = sigm(pf), gg = tanh_fast(pg), og = sigm(po);
      float cn = fg * cst[cc] + ig * gg;
      cst[cc] = cn;
      hh[cc] = og * tanh_fast(cn) * fac[cc];
    }

    // ---- eviction guard: layer above finished reading our hLLC slot (t-2)
    if (l < 3 && t >= 2)
      pollcnt(CNT(2, g + 4, (t - 2) & 7), tgt_of(t - 2), true);

    // ---- dual h store (always both) + split publishes ----
    {
      uint32_t pkv = (uint32_t)f2h(hh[0]) | ((uint32_t)f2h(hh[1]) << 16);
      const int elem = iwg * 512 + hi * 256 + n * 8 + wave * 2;   // shorts
      unsigned short* wL2  = P.hL2  + (size_t)(g * 2 + (t & 1)) * 16384 + elem;
      unsigned short* wLLC = P.hLLC + (size_t)(g * 2 + (t & 1)) * 16384 + elem;
      asm volatile("global_store_dword %0, %1, off sc0" :: "v"(wL2), "v"(pkv) : "memory");
      asm volatile("global_store_dword %0, %1, off sc0 sc1" :: "v"(wLLC), "v"(pkv) : "memory");
      asm volatile("s_waitcnt vmcnt(1)" ::: "memory");   // hL2 store (issued first) acked
    }
    __syncthreads();
    if (tid == 0)   // own-ready (L2 copy visible to same-XCD group)
      __hip_atomic_fetch_add(CNT(0, g, t & 7), 1u, __ATOMIC_RELAXED, __HIP_MEMORY_SCOPE_AGENT);
    asm volatile("s_waitcnt vmcnt(0)" ::: "memory");
    __syncthreads();
    if (tid == 0)   // full-ready (LLC copy): below edge + fallback own edge
      __hip_atomic_fetch_add(CNT(1, g, t & 7), 1u, __ATOMIC_RELAXED, __HIP_MEMORY_SCOPE_AGENT);

    // ---- layer-3 projection (after publish) ----
    if (l == 3) {
      float osum = hh[0] * wlin_s[k0] + hh[1] * wlin_s[k0 + 1];
      red_s[wave][lane] = osum;
      __syncthreads();
      if (tid < 32) {
        float v = red_s[0][tid] + red_s[1][tid] + red_s[2][tid] + red_s[3][tid]
                + red_s[0][32 + tid] + red_s[1][32 + tid] + red_s[2][32 + tid] + red_s[3][32 + tid];
        if (iwg == 0) v += P.b_lin[0];
        atomicAdd(&P.out[(q * 32 + tid) * 512 + t], v);
      }
    }
  }
#undef CNT
}

extern "C" void kernel_launch(void* const* d_in, const int* in_sizes, int n_in,
                              void* d_out, int out_size, void* d_ws, size_t ws_size,
                              hipStream_t stream) {
  (void)in_sizes; (void)n_in; (void)ws_size;
  KParams P;
  P.input = (const float*)d_in[0];
  for (int l = 0; l < 4; ++l) {
    P.w_ih[l] = (const float*)d_in[1 + 4 * l];
    P.w_hh[l] = (const float*)d_in[2 + 4 * l];
    P.b_ih[l] = (const float*)d_in[3 + 4 * l];
    P.b_hh[l] = (const float*)d_in[4 + 4 * l];
  }
  P.w_lin = (const float*)d_in[17];
  P.b_lin = (const float*)d_in[18];
  unsigned char* ws = (unsigned char*)d_ws;
  P.hLLC    = (unsigned short*)(ws);                          // 1 MB   [16][2][16384] fp16
  P.hL2     = (unsigned short*)(ws + (1u << 20));             // 1 MB
  P.cnt     = (uint32_t*)(ws + (2u << 20));                   // 48 KB  [3][16][8] x 128B
  P.xcdtab  = (uint32_t*)(ws + (2u << 20) + (48u << 10));     // 2 KB   [512]
  P.initcnt = (uint32_t*)(ws + (2u << 20) + (50u << 10));
  P.out     = (float*)d_out;
  // total ws span ~2.05 MB (<= 2.62 MB proven by R2/R3)

  // subkeys = jax.random.split(key(42), 4) under threefry_partitionable=True
  for (uint32_t i = 0; i < 4; ++i) {
    uint32_t x0 = 0u, x1 = i;
    tf2x32(0u, 42u, x0, x1);
    P.mk[i][0] = x0; P.mk[i][1] = x1;
  }

  hipMemsetAsync(P.cnt, 0, (48u << 10) + 4096, stream);       // counters + xcdtab + initcnt
  hipMemsetAsync(d_out, 0, (size_t)out_size * sizeof(float), stream);
  hipLaunchKernelGGL(lstm4, dim3(512), dim3(256), 0, stream, P);
}

// Round 12
// 2798.811 us; speedup vs baseline: 1.2765x; 1.2362x over previous
//
#include <hip/hip_runtime.h>
#include <cstdint>

#define TT 512

typedef float f32x16 __attribute__((ext_vector_type(16)));
typedef short s16x8 __attribute__((ext_vector_type(8)));
typedef _Float16 f16x8 __attribute__((ext_vector_type(8)));

// ---------------- threefry2x32 (exact JAX semantics) ----------------
__host__ __device__ inline void tf2x32(uint32_t k0, uint32_t k1, uint32_t& x0, uint32_t& x1) {
  uint32_t k2 = k0 ^ k1 ^ 0x1BD11BDAu;
#define TF_R(r) { x0 += x1; x1 = (x1 << r) | (x1 >> (32 - r)); x1 ^= x0; }
  x0 += k0; x1 += k1;
  TF_R(13) TF_R(15) TF_R(26) TF_R(6)
  x0 += k1; x1 += k2 + 1u;
  TF_R(17) TF_R(29) TF_R(16) TF_R(24)
  x0 += k2; x1 += k0 + 2u;
  TF_R(13) TF_R(15) TF_R(26) TF_R(6)
  x0 += k0; x1 += k1 + 3u;
  TF_R(17) TF_R(29) TF_R(16) TF_R(24)
  x0 += k1; x1 += k2 + 4u;
  TF_R(13) TF_R(15) TF_R(26) TF_R(6)
  x0 += k2; x1 += k0 + 5u;
#undef TF_R
}

struct KParams {
  const float* input;
  const float* w_ih[4];
  const float* w_hh[4];
  const float* b_ih[4];
  const float* b_hh[4];
  const float* w_lin;
  const float* b_lin;
  unsigned short* hbuf;   // [8][2][32768] fp16 — LLC-coherent h exchange (sc0 sc1)
  uint32_t* cnt;          // kinds: 0=stores-done 1=reads-done; [2][8][8] x 32 dwords
  float* out;             // [128][512]
  uint32_t mk[4][2];      // per-layer threefry subkeys (partitionable split)
};

__device__ __forceinline__ unsigned short f2h(float v) {
  _Float16 h = (_Float16)v;
  return __builtin_bit_cast(unsigned short, h);
}
__device__ __forceinline__ float sigm(float x) { return 1.f / (1.f + __expf(-x)); }
__device__ __forceinline__ float tanh_fast(float x) {
  float a = fabsf(x);
  float e = __expf(-2.f * a);
  float r = (1.f - e) / (1.f + e);
  return copysignf(r, x);
}

#define MFMA16(A, B, C) __builtin_amdgcn_mfma_f32_32x32x16_f16((A), (B), (C), 0, 0, 0)

// counted vmcnt wait (a = pipeline iterations allowed in flight; 2 loads/iter)
__device__ __forceinline__ void vmwait_dyn(int a) {
  switch (a) {
    case 0: asm volatile("s_waitcnt vmcnt(0)" ::: "memory"); break;
    case 1: asm volatile("s_waitcnt vmcnt(2)" ::: "memory"); break;
    case 2: asm volatile("s_waitcnt vmcnt(4)" ::: "memory"); break;
    case 3: asm volatile("s_waitcnt vmcnt(6)" ::: "memory"); break;
    case 4: asm volatile("s_waitcnt vmcnt(8)" ::: "memory"); break;
    case 5: asm volatile("s_waitcnt vmcnt(10)" ::: "memory"); break;
    case 6: asm volatile("s_waitcnt vmcnt(12)" ::: "memory"); break;
    default: asm volatile("s_waitcnt vmcnt(14)" ::: "memory"); break;
  }
  __builtin_amdgcn_sched_barrier(0);
}

#define ISSUE2(s0, s1, ptr) \
  asm volatile("global_load_dwordx4 %0, %2, off sc0 sc1\n\t" \
               "global_load_dwordx4 %1, %2, off offset:1024 sc0 sc1" \
               : "=&v"(s0), "=&v"(s1) : "v"(ptr) : "memory")

// 8-iteration GEMM half (fp16 single-term): frags FRAGBASE..FRAGBASE+7.
// PRECONDITION: vmcnt == 0 on entry.
template <int FRAGBASE>
__device__ __forceinline__ void gemm8(const unsigned short* buf,
                                      const f16x8 (&W)[2][16],
                                      int wave, int lane,
                                      f32x16& a00, f32x16& a01, f32x16& a10, f32x16& a11) {
  s16x8 st[8][2];
  const int lofs = wave * 1024 + lane * 8;   // k-block = i*4 + wave
#pragma unroll
  for (int i = 0; i < 8; ++i) {
    const unsigned short* p = buf + i * 4096 + lofs;
    ISSUE2(st[i][0], st[i][1], p);
  }
#pragma unroll
  for (int i = 0; i < 8; ++i) {
    vmwait_dyn(7 - i);
    f16x8 b0 = __builtin_bit_cast(f16x8, st[i][0]);
    f16x8 b1 = __builtin_bit_cast(f16x8, st[i][1]);
    a00 = MFMA16(W[0][FRAGBASE + i], b0, a00);
    a10 = MFMA16(W[1][FRAGBASE + i], b0, a10);
    a01 = MFMA16(W[0][FRAGBASE + i], b1, a01);
    a11 = MFMA16(W[1][FRAGBASE + i], b1, a11);
  }
}

// single-dword monotone-counter poll (all lanes same address -> broadcast)
__device__ __forceinline__ void pollcnt(const uint32_t* p, uint32_t tgt, bool slp) {
  while (__hip_atomic_load(p, __ATOMIC_RELAXED, __HIP_MEMORY_SCOPE_AGENT) < tgt) {
    if (slp) __builtin_amdgcn_s_sleep(1);
  }
}
__device__ __forceinline__ uint32_t tgt_of(int T) { return 32u * ((uint32_t)(T >> 3) + 1u); }

__global__ __launch_bounds__(256, 1) void lstm4(KParams P) {
  const int wg   = blockIdx.x;
  const int grp  = wg & 7;       // (layer, half)
  const int iwg  = wg >> 3;      // 0..31: which 16-unit slice (= its k-block)
  const int l    = grp >> 1;
  const int p    = grp & 1;
  const int tid  = threadIdx.x;
  const int wave = tid >> 6;
  const int lane = tid & 63;

  __shared__ float part[4][64][64];   // 64 KB: per-wave k-split partials, single phase
  __shared__ float bias_s[64];
  __shared__ float wih1_s[64];
  __shared__ float wlin_s[16];
  __shared__ float red_s[4][64];

#define CNT(kind, g, slot) (P.cnt + (((kind) * 8 + (g)) * 8 + (slot)) * 32)

  // ---- fp16 weight fragments into registers (single term, 128 VGPR total)
  // frags 0..7 = below half (w_ih, l>0); frags 8..15 = own half (w_hh); l==0: 0..7 = w_hh
  f16x8 W[2][16];
  {
#pragma unroll
    for (int ji = 0; ji < 16; ++ji) {
      const bool valid = (l > 0) || (ji < 8);
      const float* wsrc = (l == 0 || ji >= 8) ? P.w_hh[l] : P.w_ih[l];
      const int blk = (ji & 7) * 4 + wave;
      const int col = blk * 16 + (lane >> 5) * 8;
#pragma unroll
      for (int m = 0; m < 2; ++m) {
        const int rl = m * 32 + (lane & 31);
        const int grow = (rl >> 4) * 512 + iwg * 16 + (rl & 15);
        f16x8 v8 = {0, 0, 0, 0, 0, 0, 0, 0};
        if (valid) {
          const float* s = wsrc + grow * 512 + col;
#pragma unroll
          for (int e = 0; e < 8; ++e) v8[e] = (_Float16)s[e];
        }
        W[m][ji] = v8;
      }
    }
  }
  if (tid < 64) {
    const int rl = tid;
    const int grow = (rl >> 4) * 512 + iwg * 16 + (rl & 15);
    bias_s[rl] = P.b_ih[l][grow] + P.b_hh[l][grow];
    wih1_s[rl] = (l == 0) ? P.w_ih[0][grow] : 0.f;
  }
  if (l == 3 && tid < 16) wlin_s[tid] = P.w_lin[iwg * 16 + tid];
  __syncthreads();

  const int gb = p * 64 + lane;
  const uint32_t kk0 = P.mk[l][0], kk1 = P.mk[l][1];
  float cst[4] = {0.f, 0.f, 0.f, 0.f};

  // dropout factors for beat 0 (subsequent beats computed post-publish of beat t-1)
  float fac[4];
#pragma unroll
  for (int cc = 0; cc < 4; ++cc) {
    const int gu = iwg * 16 + wave * 4 + cc;
    uint32_t j = (uint32_t)gb * 512u + (uint32_t)gu;
    uint32_t x0 = 0u, x1 = j;
    tf2x32(kk0, kk1, x0, x1);
    fac[cc] = ((x0 ^ x1) & 0x80000000u) ? 0.f : 2.f;
  }

  for (int t = 0; t < TT; ++t) {
    float xin = 0.f;
    if (l == 0) xin = P.input[gb * 512 + t];

    f32x16 a00 = {0,0,0,0,0,0,0,0,0,0,0,0,0,0,0,0};
    f32x16 a01 = {0,0,0,0,0,0,0,0,0,0,0,0,0,0,0,0};
    f32x16 a10 = {0,0,0,0,0,0,0,0,0,0,0,0,0,0,0,0};
    f32x16 a11 = {0,0,0,0,0,0,0,0,0,0,0,0,0,0,0,0};

    const unsigned short* pB = P.hbuf + (size_t)(((l - 1) * 2 + p) * 2 + (t & 1)) * 32768;
    const unsigned short* pO = P.hbuf + (size_t)(grp * 2 + ((t - 1) & 1)) * 32768;

    // ---- phase A: below half (cross-layer edge, pipeline slack)
    if (l > 0) {
      pollcnt(CNT(0, grp - 2, t & 7), tgt_of(t), true);
      asm volatile("s_waitcnt vmcnt(0)" ::: "memory");
      gemm8<0>(pB, W, wave, lane, a00, a01, a10, a11);
    }
    // ---- phase B: own half (critical recurrent edge; hot poll)
    if (t > 0) {
      pollcnt(CNT(0, grp, (t - 1) & 7), tgt_of(t - 1), false);
      asm volatile("s_waitcnt vmcnt(0)" ::: "memory");
      if (l > 0) gemm8<8>(pO, W, wave, lane, a00, a01, a10, a11);
      else       gemm8<0>(pO, W, wave, lane, a00, a01, a10, a11);
    }

    // ---- single-phase cross-wave k-split reduction ----
#pragma unroll
    for (int r = 0; r < 16; ++r) {
      const int row = (r & 3) + 8 * (r >> 2) + 4 * (lane >> 5);
      const int cl = lane & 31;
      part[wave][row][cl]           = a00[r];
      part[wave][row][32 + cl]      = a01[r];
      part[wave][32 + row][cl]      = a10[r];
      part[wave][32 + row][32 + cl] = a11[r];
    }
    __syncthreads();
    // reads-done publish: all waves' GEMM loads retired (each gemm8 ends at vmcnt(0))
    if (tid == 0 && l > 0)
      __hip_atomic_fetch_add(CNT(1, grp, t & 7), 1u, __ATOMIC_RELAXED, __HIP_MEMORY_SCOPE_AGENT);

    float si[4], sf[4], sg[4], so[4];
#pragma unroll
    for (int cc = 0; cc < 4; ++cc) {
      const int ul = wave * 4 + cc;
      si[cc] = part[0][ul][lane]      + part[1][ul][lane]      + part[2][ul][lane]      + part[3][ul][lane];
      sf[cc] = part[0][16 + ul][lane] + part[1][16 + ul][lane] + part[2][16 + ul][lane] + part[3][16 + ul][lane];
      sg[cc] = part[0][32 + ul][lane] + part[1][32 + ul][lane] + part[2][32 + ul][lane] + part[3][32 + ul][lane];
      so[cc] = part[0][48 + ul][lane] + part[1][48 + ul][lane] + part[2][48 + ul][lane] + part[3][48 + ul][lane];
    }

    // ---- elementwise LSTM cell (fac precomputed last beat) ----
    float osum = 0.f;
    unsigned short hv[4];
#pragma unroll
    for (int cc = 0; cc < 4; ++cc) {
      const int ul = wave * 4 + cc;
      float pi = si[cc] + bias_s[ul];
      float pf = sf[cc] + bias_s[16 + ul];
      float pg = sg[cc] + bias_s[32 + ul];
      float po = so[cc] + bias_s[48 + ul];
      if (l == 0) {
        pi += wih1_s[ul] * xin;
        pf += wih1_s[16 + ul] * xin;
        pg += wih1_s[32 + ul] * xin;
        po += wih1_s[48 + ul] * xin;
      }
      float ig = sigm(pi), fg = sigm(pf), gg = tanh_fast(pg), og = sigm(po);
      float cn = fg * cst[cc] + ig * gg;
      cst[cc] = cn;
      float hh = og * tanh_fast(cn) * fac[cc];
      hv[cc] = f2h(hh);
      if (l == 3) osum += hh * wlin_s[ul];
    }

    // ---- eviction guard: layer above finished reading our slot (t-2)
    if (l < 3 && t >= 2)
      pollcnt(CNT(1, grp + 2, (t - 2) & 7), tgt_of(t - 2), true);

    // ---- single h store + drain + stores-done publish ----
    {
      uint32_t d0 = (uint32_t)hv[0] | ((uint32_t)hv[1] << 16);
      uint32_t d1 = (uint32_t)hv[2] | ((uint32_t)hv[3] << 16);
      typedef uint32_t u32x2 __attribute__((ext_vector_type(2)));
      u32x2 dv = {d0, d1};
      const int elem = ((iwg * 2 + (lane >> 5)) * 64 + (wave >> 1) * 32 + (lane & 31)) * 8 + (wave & 1) * 4;
      unsigned short* wb = P.hbuf + (size_t)(grp * 2 + (t & 1)) * 32768 + elem;
      asm volatile("global_store_dwordx2 %0, %1, off sc0 sc1" :: "v"(wb), "v"(dv) : "memory");
      asm volatile("s_waitcnt vmcnt(0)" ::: "memory");
    }
    __syncthreads();
    if (tid == 0)
      __hip_atomic_fetch_add(CNT(0, grp, t & 7), 1u, __ATOMIC_RELAXED, __HIP_MEMORY_SCOPE_AGENT);

    // ---- layer-3 projection (after publish) ----
    if (l == 3) {
      red_s[wave][lane] = osum;
      __syncthreads();
      if (tid < 64) {
        float v = red_s[0][tid] + red_s[1][tid] + red_s[2][tid] + red_s[3][tid];
        if (iwg == 0) v += P.b_lin[0];
        atomicAdd(&P.out[(p * 64 + tid) * 512 + t], v);
      }
    }

    // ---- threefry for beat t+1 — overlaps next-beat flag waits ----
    if (t + 1 < TT) {
#pragma unroll
      for (int cc = 0; cc < 4; ++cc) {
        const int gu = iwg * 16 + wave * 4 + cc;
        uint32_t j = ((uint32_t)(t + 1) * 128u + (uint32_t)gb) * 512u + (uint32_t)gu;
        uint32_t x0 = 0u, x1 = j;
        tf2x32(kk0, kk1, x0, x1);
        fac[cc] = ((x0 ^ x1) & 0x80000000u) ? 0.f : 2.f;
      }
    }
  }
#undef CNT
}

extern "C" void kernel_launch(void* const* d_in, const int* in_sizes, int n_in,
                              void* d_out, int out_size, void* d_ws, size_t ws_size,
                              hipStream_t stream) {
  (void)in_sizes; (void)n_in; (void)ws_size;
  KParams P;
  P.input = (const float*)d_in[0];
  for (int l = 0; l < 4; ++l) {
    P.w_ih[l] = (const float*)d_in[1 + 4 * l];
    P.w_hh[l] = (const float*)d_in[2 + 4 * l];
    P.b_ih[l] = (const float*)d_in[3 + 4 * l];
    P.b_hh[l] = (const float*)d_in[4 + 4 * l];
  }
  P.w_lin = (const float*)d_in[17];
  P.b_lin = (const float*)d_in[18];
  unsigned char* ws = (unsigned char*)d_ws;
  P.hbuf = (unsigned short*)(ws);                  // 1 MB   [8][2][32768] fp16
  P.cnt  = (uint32_t*)(ws + (1u << 20));           // 16 KB  [2][8][8] x 128B
  P.out  = (float*)d_out;
  // total ws span ~1.02 MB (well under proven 2.62 MB)

  // subkeys = jax.random.split(key(42), 4) under threefry_partitionable=True
  for (uint32_t i = 0; i < 4; ++i) {
    uint32_t x0 = 0u, x1 = i;
    tf2x32(0u, 42u, x0, x1);
    P.mk[i][0] = x0; P.mk[i][1] = x1;
  }

  hipMemsetAsync(P.cnt, 0, 2 * 8 * 8 * 32 * sizeof(uint32_t), stream);
  hipMemsetAsync(d_out, 0, (size_t)out_size * sizeof(float), stream);
  hipLaunchKernelGGL(lstm4, dim3(256), dim3(256), 0, stream, P);
}

// Round 14
// 2533.204 us; speedup vs baseline: 1.4103x; 1.1049x over previous
//
#include <hip/hip_runtime.h>
#include <cstdint>

#define TT 512

typedef float f32x16 __attribute__((ext_vector_type(16)));
typedef float f32x4 __attribute__((ext_vector_type(4)));
typedef short s16x8 __attribute__((ext_vector_type(8)));
typedef _Float16 f16x8 __attribute__((ext_vector_type(8)));
typedef uint32_t u32x2 __attribute__((ext_vector_type(2)));

// ---------------- threefry2x32 (exact JAX semantics) ----------------
__host__ __device__ inline void tf2x32(uint32_t k0, uint32_t k1, uint32_t& x0, uint32_t& x1) {
  uint32_t k2 = k0 ^ k1 ^ 0x1BD11BDAu;
#define TF_R(r) { x0 += x1; x1 = (x1 << r) | (x1 >> (32 - r)); x1 ^= x0; }
  x0 += k0; x1 += k1;
  TF_R(13) TF_R(15) TF_R(26) TF_R(6)
  x0 += k1; x1 += k2 + 1u;
  TF_R(17) TF_R(29) TF_R(16) TF_R(24)
  x0 += k2; x1 += k0 + 2u;
  TF_R(13) TF_R(15) TF_R(26) TF_R(6)
  x0 += k0; x1 += k1 + 3u;
  TF_R(17) TF_R(29) TF_R(16) TF_R(24)
  x0 += k1; x1 += k2 + 4u;
  TF_R(13) TF_R(15) TF_R(26) TF_R(6)
  x0 += k2; x1 += k0 + 5u;
#undef TF_R
}

struct KParams {
  const float* input;
  const float* w_ih[4];
  const float* w_hh[4];
  const float* b_ih[4];
  const float* b_hh[4];
  const float* w_lin;
  const float* b_lin;
  unsigned short* hbuf;   // [8][2][32768] fp16 — LLC-coherent h exchange (sc0 sc1)
  uint32_t* cnt;          // kinds: 0=stores-done 1=reads-done; [2][8][8] x 32 dwords
  float* out;             // [128][512]
  uint32_t mk[4][2];      // per-layer threefry subkeys (partitionable split)
};

__device__ __forceinline__ unsigned short f2h(float v) {
  _Float16 h = (_Float16)v;
  return __builtin_bit_cast(unsigned short, h);
}
__device__ __forceinline__ float sigm(float x) { return 1.f / (1.f + __expf(-x)); }
__device__ __forceinline__ float tanh_fast(float x) {
  float a = fabsf(x);
  float e = __expf(-2.f * a);
  float r = (1.f - e) / (1.f + e);
  return copysignf(r, x);
}

#define MFMA16(A, B, C) __builtin_amdgcn_mfma_f32_32x32x16_f16((A), (B), (C), 0, 0, 0)

// counted vmcnt wait (a = load-pairs still allowed in flight; 2 loads/pair)
__device__ __forceinline__ void vmwait_dyn(int a) {
  switch (a) {
    case 0: asm volatile("s_waitcnt vmcnt(0)" ::: "memory"); break;
    case 1: asm volatile("s_waitcnt vmcnt(2)" ::: "memory"); break;
    case 2: asm volatile("s_waitcnt vmcnt(4)" ::: "memory"); break;
    case 3: asm volatile("s_waitcnt vmcnt(6)" ::: "memory"); break;
    case 4: asm volatile("s_waitcnt vmcnt(8)" ::: "memory"); break;
    case 5: asm volatile("s_waitcnt vmcnt(10)" ::: "memory"); break;
    case 6: asm volatile("s_waitcnt vmcnt(12)" ::: "memory"); break;
    default: asm volatile("s_waitcnt vmcnt(14)" ::: "memory"); break;
  }
  __builtin_amdgcn_sched_barrier(0);
}

#define ISSUE2(s0, s1, ptr) \
  asm volatile("global_load_dwordx4 %0, %2, off sc0 sc1\n\t" \
               "global_load_dwordx4 %1, %2, off offset:1024 sc0 sc1" \
               : "=&v"(s0), "=&v"(s1) : "v"(ptr) : "memory")

// issue 8 load-pairs for a GEMM half
__device__ __forceinline__ void issue8(const unsigned short* buf, int lofs, s16x8 (&st)[8][2]) {
#pragma unroll
  for (int i = 0; i < 8; ++i) {
    const unsigned short* p = buf + i * 4096 + lofs;
    ISSUE2(st[i][0], st[i][1], p);
  }
}
// consume 8 pairs with NO waits. PRECONDITION: pairs already landed (a dynamic
// vmcnt(0) executed after their issue). sched_barrier(0) pins the MFMAs after
// this program point so the compiler cannot hoist them above that wait (rule #18).
template <int FRAGBASE>
__device__ __forceinline__ void mfma8_nowait(const s16x8 (&st)[8][2], const f16x8 (&W)[2][16],
                                             f32x16& a00, f32x16& a01, f32x16& a10, f32x16& a11) {
  __builtin_amdgcn_sched_barrier(0);
#pragma unroll
  for (int i = 0; i < 8; ++i) {
    f16x8 b0 = __builtin_bit_cast(f16x8, st[i][0]);
    f16x8 b1 = __builtin_bit_cast(f16x8, st[i][1]);
    a00 = MFMA16(W[0][FRAGBASE + i], b0, a00);
    a10 = MFMA16(W[1][FRAGBASE + i], b0, a10);
    a01 = MFMA16(W[0][FRAGBASE + i], b1, a01);
    a11 = MFMA16(W[1][FRAGBASE + i], b1, a11);
  }
}
// consume 8 pairs with counted waits (PRECONDITION: exactly these 8 pairs in flight)
template <int FRAGBASE>
__device__ __forceinline__ void mfma8_counted(const s16x8 (&st)[8][2], const f16x8 (&W)[2][16],
                                              f32x16& a00, f32x16& a01, f32x16& a10, f32x16& a11) {
#pragma unroll
  for (int i = 0; i < 8; ++i) {
    vmwait_dyn(7 - i);
    f16x8 b0 = __builtin_bit_cast(f16x8, st[i][0]);
    f16x8 b1 = __builtin_bit_cast(f16x8, st[i][1]);
    a00 = MFMA16(W[0][FRAGBASE + i], b0, a00);
    a10 = MFMA16(W[1][FRAGBASE + i], b0, a10);
    a01 = MFMA16(W[0][FRAGBASE + i], b1, a01);
    a11 = MFMA16(W[1][FRAGBASE + i], b1, a11);
  }
}

// single-dword monotone-counter poll (all lanes same address -> broadcast)
__device__ __forceinline__ void pollcnt(const uint32_t* p, uint32_t tgt, bool slp) {
  while (__hip_atomic_load(p, __ATOMIC_RELAXED, __HIP_MEMORY_SCOPE_AGENT) < tgt) {
    if (slp) __builtin_amdgcn_s_sleep(1);
  }
}
__device__ __forceinline__ bool samplecnt(const uint32_t* p, uint32_t tgt) {
  return __hip_atomic_load(p, __ATOMIC_RELAXED, __HIP_MEMORY_SCOPE_AGENT) >= tgt;
}
__device__ __forceinline__ uint32_t tgt_of(int T) { return 32u * ((uint32_t)(T >> 3) + 1u); }

__global__ __launch_bounds__(256, 1) void lstm4(KParams P) {
  const int wg   = blockIdx.x;
  const int grp  = wg & 7;       // (layer, half)
  const int iwg  = wg >> 3;      // 0..31: which 16-unit slice (= its k-block)
  const int l    = grp >> 1;
  const int p    = grp & 1;
  const int tid  = threadIdx.x;
  const int wave = tid >> 6;
  const int lane = tid & 63;
  const int cl   = lane & 31;
  const int hi   = lane >> 5;

  __shared__ f32x4 part2[4][64][17];   // 68 KB: [wave][batch][gate-col/4], transposed
  __shared__ float bias_s[64];
  __shared__ float wih1_s[64];
  __shared__ float wlin_s[16];
  __shared__ float red_s[4][64];

#define CNT(kind, g, slot) (P.cnt + (((kind) * 8 + (g)) * 8 + (slot)) * 32)

  // ---- fp16 weight fragments into registers (single term)
  // frags 0..7 = below half (w_ih, l>0); frags 8..15 = own half (w_hh); l==0: 0..7 = w_hh
  f16x8 W[2][16];
  {
#pragma unroll
    for (int ji = 0; ji < 16; ++ji) {
      const bool valid = (l > 0) || (ji < 8);
      const float* wsrc = (l == 0 || ji >= 8) ? P.w_hh[l] : P.w_ih[l];
      const int blk = (ji & 7) * 4 + wave;
      const int col = blk * 16 + hi * 8;
#pragma unroll
      for (int m = 0; m < 2; ++m) {
        const int rl = m * 32 + cl;
        const int grow = (rl >> 4) * 512 + iwg * 16 + (rl & 15);
        f16x8 v8 = {0, 0, 0, 0, 0, 0, 0, 0};
        if (valid) {
          const float* s = wsrc + grow * 512 + col;
#pragma unroll
          for (int e = 0; e < 8; ++e) v8[e] = (_Float16)s[e];
        }
        W[m][ji] = v8;
      }
    }
  }
  if (tid < 64) {
    const int rl = tid;
    const int grow = (rl >> 4) * 512 + iwg * 16 + (rl & 15);
    bias_s[rl] = P.b_ih[l][grow] + P.b_hh[l][grow];
    wih1_s[rl] = (l == 0) ? P.w_ih[0][grow] : 0.f;
  }
  if (l == 3 && tid < 16) wlin_s[tid] = P.w_lin[iwg * 16 + tid];
  __syncthreads();

  const int gb = p * 64 + lane;
  const uint32_t kk0 = P.mk[l][0], kk1 = P.mk[l][1];
  const int lofs = wave * 1024 + lane * 8;
  const int elem = ((iwg * 2 + hi) * 64 + (wave >> 1) * 32 + cl) * 8 + (wave & 1) * 4;
  float cst[4] = {0.f, 0.f, 0.f, 0.f};

  // dropout factors for beat 0 (later beats computed post-publish)
  float fac[4];
#pragma unroll
  for (int cc = 0; cc < 4; ++cc) {
    const int gu = iwg * 16 + wave * 4 + cc;
    uint32_t j = (uint32_t)gb * 512u + (uint32_t)gu;
    uint32_t x0 = 0u, x1 = j;
    tf2x32(kk0, kk1, x0, x1);
    fac[cc] = ((x0 ^ x1) & 0x80000000u) ? 0.f : 2.f;
  }

  s16x8 stB[8][2], stO[8][2];

  for (int t = 0; t < TT; ++t) {
    float xin = 0.f;
    if (l == 0) xin = P.input[gb * 512 + t];

    f32x16 a00 = {0,0,0,0,0,0,0,0,0,0,0,0,0,0,0,0};
    f32x16 a01 = {0,0,0,0,0,0,0,0,0,0,0,0,0,0,0,0};
    f32x16 a10 = {0,0,0,0,0,0,0,0,0,0,0,0,0,0,0,0};
    f32x16 a11 = {0,0,0,0,0,0,0,0,0,0,0,0,0,0,0,0};

    const unsigned short* pB = P.hbuf + (size_t)(((l - 1) * 2 + p) * 2 + (t & 1)) * 32768;
    const unsigned short* pO = P.hbuf + (size_t)(grp * 2 + ((t - 1) & 1)) * 32768;

    if (l > 0) {
      pollcnt(CNT(0, grp - 2, t & 7), tgt_of(t), true);      // below edge (slack)
      issue8(pB, lofs, stB);
      if (t > 0) {
        // sample own flag; the compiler's vmcnt(0) for this value (before the
        // branch) also drains the stB loads — shared round trip
        if (samplecnt(CNT(0, grp, (t - 1) & 7), tgt_of(t - 1))) {
          issue8(pO, lofs, stO);                             // own RT hides under below MFMA
          mfma8_nowait<0>(stB, W, a00, a01, a10, a11);
          mfma8_counted<8>(stO, W, a00, a01, a10, a11);
        } else {
          mfma8_nowait<0>(stB, W, a00, a01, a10, a11);
          pollcnt(CNT(0, grp, (t - 1) & 7), tgt_of(t - 1), false);
          issue8(pO, lofs, stO);
          mfma8_counted<8>(stO, W, a00, a01, a10, a11);
        }
      } else {
        mfma8_counted<0>(stB, W, a00, a01, a10, a11);        // counted: no fence hazard
      }
    } else if (t > 0) {
      pollcnt(CNT(0, grp, (t - 1) & 7), tgt_of(t - 1), false);  // critical edge, hot
      issue8(pO, lofs, stO);
      mfma8_counted<0>(stO, W, a00, a01, a10, a11);
    }

    // ---- transposed k-split reduction: 16 ds_write_b128 ----
#pragma unroll
    for (int rs = 0; rs < 4; ++rs) {
      f32x4 v00 = {a00[4 * rs], a00[4 * rs + 1], a00[4 * rs + 2], a00[4 * rs + 3]};
      f32x4 v01 = {a01[4 * rs], a01[4 * rs + 1], a01[4 * rs + 2], a01[4 * rs + 3]};
      f32x4 v10 = {a10[4 * rs], a10[4 * rs + 1], a10[4 * rs + 2], a10[4 * rs + 3]};
      f32x4 v11 = {a11[4 * rs], a11[4 * rs + 1], a11[4 * rs + 2], a11[4 * rs + 3]};
      const int cb = 2 * rs + hi;
      part2[wave][cl][cb]          = v00;
      part2[wave][cl + 32][cb]     = v01;
      part2[wave][cl][8 + cb]      = v10;
      part2[wave][cl + 32][8 + cb] = v11;
    }
    __syncthreads();
    // reads-done publish: all waves' GEMM loads retired (every path ends at vmcnt(0))
    if (tid == 0 && l > 0)
      __hip_atomic_fetch_add(CNT(1, grp, t & 7), 1u, __ATOMIC_RELAXED, __HIP_MEMORY_SCOPE_AGENT);

    // ---- 16 ds_read_b128 + f32x4 sums ----
    f32x4 si4 = part2[0][lane][wave]      + part2[1][lane][wave]      + part2[2][lane][wave]      + part2[3][lane][wave];
    f32x4 sf4 = part2[0][lane][4 + wave]  + part2[1][lane][4 + wave]  + part2[2][lane][4 + wave]  + part2[3][lane][4 + wave];
    f32x4 sg4 = part2[0][lane][8 + wave]  + part2[1][lane][8 + wave]  + part2[2][lane][8 + wave]  + part2[3][lane][8 + wave];
    f32x4 so4 = part2[0][lane][12 + wave] + part2[1][lane][12 + wave] + part2[2][lane][12 + wave] + part2[3][lane][12 + wave];

    // ---- elementwise LSTM cell (fac precomputed last beat) ----
    float osum = 0.f;
    unsigned short hv[4];
#pragma unroll
    for (int cc = 0; cc < 4; ++cc) {
      const int ul = wave * 4 + cc;
      float pi = si4[cc] + bias_s[ul];
      float pf = sf4[cc] + bias_s[16 + ul];
      float pg = sg4[cc] + bias_s[32 + ul];
      float po = so4[cc] + bias_s[48 + ul];
      if (l == 0) {
        pi += wih1_s[ul] * xin;
        pf += wih1_s[16 + ul] * xin;
        pg += wih1_s[32 + ul] * xin;
        po += wih1_s[48 + ul] * xin;
      }
      float ig = sigm(pi), fg = sigm(pf), gg = tanh_fast(pg), og = sigm(po);
      float cn = fg * cst[cc] + ig * gg;
      cst[cc] = cn;
      float hh = og * tanh_fast(cn) * fac[cc];
      hv[cc] = f2h(hh);
      if (l == 3) osum += hh * wlin_s[ul];
    }

    // ---- eviction guard: layer above finished reading our slot (t-2)
    if (l < 3 && t >= 2)
      pollcnt(CNT(1, grp + 2, (t - 2) & 7), tgt_of(t - 2), true);

    // ---- single h store + drain + stores-done publish ----
    {
      uint32_t d0 = (uint32_t)hv[0] | ((uint32_t)hv[1] << 16);
      uint32_t d1 = (uint32_t)hv[2] | ((uint32_t)hv[3] << 16);
      u32x2 dv = {d0, d1};
      unsigned short* wb = P.hbuf + (size_t)(grp * 2 + (t & 1)) * 32768 + elem;
      asm volatile("global_store_dwordx2 %0, %1, off sc0 sc1" :: "v"(wb), "v"(dv) : "memory");
      asm volatile("s_waitcnt vmcnt(0)" ::: "memory");
    }
    __syncthreads();
    if (tid == 0)
      __hip_atomic_fetch_add(CNT(0, grp, t & 7), 1u, __ATOMIC_RELAXED, __HIP_MEMORY_SCOPE_AGENT);

    // ---- layer-3 projection (after publish) ----
    if (l == 3) {
      red_s[wave][lane] = osum;
      __syncthreads();
      if (tid < 64) {
        float v = red_s[0][tid] + red_s[1][tid] + red_s[2][tid] + red_s[3][tid];
        if (iwg == 0) v += P.b_lin[0];
        atomicAdd(&P.out[(p * 64 + tid) * 512 + t], v);
      }
    }

    // ---- threefry for beat t+1 — overlaps next-beat flag waits ----
    if (t + 1 < TT) {
#pragma unroll
      for (int cc = 0; cc < 4; ++cc) {
        const int gu = iwg * 16 + wave * 4 + cc;
        uint32_t j = ((uint32_t)(t + 1) * 128u + (uint32_t)gb) * 512u + (uint32_t)gu;
        uint32_t x0 = 0u, x1 = j;
        tf2x32(kk0, kk1, x0, x1);
        fac[cc] = ((x0 ^ x1) & 0x80000000u) ? 0.f : 2.f;
      }
    }
  }
#undef CNT
}

extern "C" void kernel_launch(void* const* d_in, const int* in_sizes, int n_in,
                              void* d_out, int out_size, void* d_ws, size_t ws_size,
                              hipStream_t stream) {
  (void)in_sizes; (void)n_in; (void)ws_size;
  KParams P;
  P.input = (const float*)d_in[0];
  for (int l = 0; l < 4; ++l) {
    P.w_ih[l] = (const float*)d_in[1 + 4 * l];
    P.w_hh[l] = (const float*)d_in[2 + 4 * l];
    P.b_ih[l] = (const float*)d_in[3 + 4 * l];
    P.b_hh[l] = (const float*)d_in[4 + 4 * l];
  }
  P.w_lin = (const float*)d_in[17];
  P.b_lin = (const float*)d_in[18];
  unsigned char* ws = (unsigned char*)d_ws;
  P.hbuf = (unsigned short*)(ws);                  // 1 MB   [8][2][32768] fp16
  P.cnt  = (uint32_t*)(ws + (1u << 20));           // 16 KB  [2][8][8] x 128B
  P.out  = (float*)d_out;

  // subkeys = jax.random.split(key(42), 4) under threefry_partitionable=True
  for (uint32_t i = 0; i < 4; ++i) {
    uint32_t x0 = 0u, x1 = i;
    tf2x32(0u, 42u, x0, x1);
    P.mk[i][0] = x0; P.mk[i][1] = x1;
  }

  hipMemsetAsync(P.cnt, 0, 2 * 8 * 8 * 32 * sizeof(uint32_t), stream);
  hipMemsetAsync(d_out, 0, (size_t)out_size * sizeof(float), stream);
  hipLaunchKernelGGL(lstm4, dim3(256), dim3(256), 0, stream, P);
}